// Round 1
// 745.614 us; speedup vs baseline: 1.0361x; 1.0361x over previous
//
#include <hip/hip_runtime.h>

// ---------------------------------------------------------------------------
// ResidualAttentionBlock forward on MI355X (gfx950).
// Round 5: split-K (atomic) for the small-grid GEMMs proj/cproj (264 -> 528
// blocks, 2 blocks/CU so barrier drains overlap), residual+bias init fused
// into the LN kernels, s_setprio around attn MFMA clusters, merged cvt.
// ---------------------------------------------------------------------------

typedef unsigned short ushort_t;
typedef __bf16 bf16x8 __attribute__((ext_vector_type(8)));
typedef float f32x4 __attribute__((ext_vector_type(4)));

#define SEQ_N   1025
#define CMODEL  1024
#define NHEAD   16
#define DH      64
#define TTOK    4100            // 1025*4 tokens
#define MP      4224            // tokens padded to 33*128
#define NPAD    1152            // seq padded to 9*128
#define BH      64              // 4*16 (batch*heads)

__device__ __forceinline__ ushort_t f2bf(float f) {
  union { float f; unsigned u; } v; v.f = f;
  unsigned r = v.u + 0x7fffu + ((v.u >> 16) & 1u);   // RNE
  return (ushort_t)(r >> 16);
}

__device__ __forceinline__ void gl_lds16(const void* g, void* s) {
  __builtin_amdgcn_global_load_lds(
      (const __attribute__((address_space(1))) unsigned int*)g,
      (__attribute__((address_space(3))) unsigned int*)s, 16, 0, 0);
}

// --------------------------- fp32 -> bf16 convert (all 4 weights) -----------
__global__ __launch_bounds__(256)
void cvt4(const float* __restrict__ s0, ushort_t* __restrict__ d0,
          const float* __restrict__ s1, ushort_t* __restrict__ d1,
          const float* __restrict__ s2, ushort_t* __restrict__ d2,
          const float* __restrict__ s3, ushort_t* __restrict__ d3) {
  const int b = blockIdx.x;
  const float* s; ushort_t* d; int off;
  if (b < 3072)      { s = s0; d = d0; off = b; }
  else if (b < 4096) { s = s1; d = d1; off = b - 3072; }
  else if (b < 8192) { s = s2; d = d2; off = b - 4096; }
  else               { s = s3; d = d3; off = b - 8192; }
  const int i = (off * 256 + threadIdx.x) * 4;
  const float4 f = *(const float4*)(s + i);
  d[i + 0] = f2bf(f.x);
  d[i + 1] = f2bf(f.y);
  d[i + 2] = f2bf(f.z);
  d[i + 3] = f2bf(f.w);
}

// --------------------------- LayerNorm (fp32 in, bf16 out) ------------------
// Optionally also writes resout[row] = row + rbias (residual+bias init for the
// following split-K GEMM's atomic accumulation).
__global__ __launch_bounds__(256)
void ln_bf(const float* __restrict__ xin, const float* __restrict__ g,
           const float* __restrict__ bb, ushort_t* __restrict__ out,
           const float* __restrict__ rbias, float* __restrict__ resout) {
  const int t = blockIdx.x;
  const float* row = xin + (size_t)t * CMODEL;
  const int base = threadIdx.x * 4;
  const float4 v = *(const float4*)(row + base);
  float s = v.x + v.y + v.z + v.w;
  float q = v.x * v.x + v.y * v.y + v.z * v.z + v.w * v.w;
#pragma unroll
  for (int off = 32; off > 0; off >>= 1) {
    s += __shfl_down(s, off);
    q += __shfl_down(q, off);
  }
  __shared__ float sh[8];
  const int wave = threadIdx.x >> 6, lane = threadIdx.x & 63;
  if (lane == 0) { sh[wave] = s; sh[4 + wave] = q; }
  __syncthreads();
  if (threadIdx.x == 0) {
    const float ts = sh[0] + sh[1] + sh[2] + sh[3];
    const float tq = sh[4] + sh[5] + sh[6] + sh[7];
    const float mean = ts * (1.f / CMODEL);
    const float var = tq * (1.f / CMODEL) - mean * mean;
    sh[0] = mean; sh[1] = rsqrtf(var + 1e-5f);
  }
  __syncthreads();
  const float mean = sh[0], rstd = sh[1];
  const float4 gg = *(const float4*)(g + base);
  const float4 bv = *(const float4*)(bb + base);
  ushort_t* orow = out + (size_t)t * CMODEL;
  orow[base + 0] = f2bf((v.x - mean) * rstd * gg.x + bv.x);
  orow[base + 1] = f2bf((v.y - mean) * rstd * gg.y + bv.y);
  orow[base + 2] = f2bf((v.z - mean) * rstd * gg.z + bv.z);
  orow[base + 3] = f2bf((v.w - mean) * rstd * gg.w + bv.w);
  if (resout) {
    const float4 rb = *(const float4*)(rbias + base);
    float4 ro;
    ro.x = v.x + rb.x; ro.y = v.y + rb.y; ro.z = v.z + rb.z; ro.w = v.w + rb.w;
    *(float4*)(resout + (size_t)t * CMODEL + base) = ro;
  }
}

// --------------------------- bf16 MFMA GEMM (C = A * B^T) -------------------
// EPI: 0=qkv scatter  3=bias+residual->fp32  4=bias+quickgelu->bf16
//      5=split-K partial: atomicAdd into pre-initialized fp32 output.
// K is the per-chunk length; blockIdx.z selects the K-chunk (kbase = z*K).
template <int EPI>
__global__ __launch_bounds__(256)
void gemm_bt(const ushort_t* __restrict__ A, int lda,
             const ushort_t* __restrict__ B, int ldb,
             int K,
             const float* __restrict__ bias, const float* __restrict__ res,
             float* __restrict__ outf, ushort_t* __restrict__ outb,
             ushort_t* __restrict__ oq, ushort_t* __restrict__ ok,
             ushort_t* __restrict__ ovt) {
  __shared__ __align__(16) ushort_t lsA[128 * 32];
  __shared__ __align__(16) ushort_t lsB[128 * 32];
  const int tid = threadIdx.x;
  const int wave = tid >> 6, lane = tid & 63;
  const int lr = lane & 15, quad = lane >> 4;
  const int tM = blockIdx.y * 128, tN = blockIdx.x * 128;
  const int kbase = blockIdx.z * K;
  const int waveM = (wave >> 1) * 64, waveN = (wave & 1) * 64;

  f32x4 acc[4][4];
  const f32x4 z4 = {0.f, 0.f, 0.f, 0.f};
#pragma unroll
  for (int i = 0; i < 4; ++i)
#pragma unroll
    for (int j = 0; j < 4; ++j) acc[i][j] = z4;

  for (int k0 = 0; k0 < K; k0 += 32) {
    __syncthreads();
#pragma unroll
    for (int p = 0; p < 2; ++p) {
      const int idx = p * 256 + wave * 64 + lane;      // chunk 0..511 (16B each)
      const int row = idx >> 2, part = idx & 3;
      const int cb = (p * 256 + wave * 64) * 8;        // wave-uniform LDS base
      gl_lds16(A + (size_t)(tM + row) * lda + kbase + k0 + part * 8, lsA + cb);
      gl_lds16(B + (size_t)(tN + row) * ldb + kbase + k0 + part * 8, lsB + cb);
    }
    __syncthreads();
    bf16x8 af[4], bfr[4];
#pragma unroll
    for (int mi = 0; mi < 4; ++mi)
      af[mi] = *(const bf16x8*)(lsA + (waveM + mi * 16 + lr) * 32 + quad * 8);
#pragma unroll
    for (int ni = 0; ni < 4; ++ni)
      bfr[ni] = *(const bf16x8*)(lsB + (waveN + ni * 16 + lr) * 32 + quad * 8);
#pragma unroll
    for (int mi = 0; mi < 4; ++mi)
#pragma unroll
      for (int ni = 0; ni < 4; ++ni)
        acc[mi][ni] = __builtin_amdgcn_mfma_f32_16x16x32_bf16(af[mi], bfr[ni], acc[mi][ni], 0, 0, 0);
  }

#pragma unroll
  for (int mi = 0; mi < 4; ++mi) {
#pragma unroll
    for (int ni = 0; ni < 4; ++ni) {
#pragma unroll
      for (int r = 0; r < 4; ++r) {
        const int m = tM + waveM + mi * 16 + quad * 4 + r;
        const int n = tN + waveN + ni * 16 + lr;
        const float v = acc[mi][ni][r];
        if constexpr (EPI == 0) {                 // qkv: scatter to q/k/v^T (bf16)
          if (m < TTOK) {
            const int b_ = m & 3, ns = m >> 2;
            const int which = n >> 10, rem = n & 1023, h = rem >> 6, d = rem & 63;
            const int bh = b_ * NHEAD + h;
            const ushort_t bv = f2bf(v);
            if (which == 0)      oq[((size_t)bh * NPAD + ns) * DH + d] = bv;
            else if (which == 1) ok[((size_t)bh * NPAD + ns) * DH + d] = bv;
            else                 ovt[((size_t)bh * DH + d) * NPAD + ns] = bv;
          }
        } else if constexpr (EPI == 3) {          // + bias + residual -> fp32
          if (m < TTOK)
            outf[(size_t)m * CMODEL + n] = v + bias[n] + res[(size_t)m * CMODEL + n];
        } else if constexpr (EPI == 4) {          // + bias, quickGELU -> bf16
          if (m < TTOK) {
            const float zv = v + bias[n];
            outb[(size_t)m * 4096 + n] = f2bf(zv / (1.f + __expf(-1.702f * zv)));
          }
        } else if constexpr (EPI == 5) {          // split-K partial -> atomic
          if (m < TTOK)
            atomicAdd(outf + (size_t)m * CMODEL + n, v);
        }
      }
    }
  }
}

// --------------------------- fused causal attention -------------------------
// Grid (bh=64, it=9). Block = 256 thr. Per block: 128 Q rows of one head.
// LDS: region0 (34816B) = K staging UNION P tile UNION lpart;
//      region1 (17408B) = Q staging, then V [64][136]; region2 = linvs (512B).
// Pass 1: S=QK^T, accumulate row sums of exp(S*scale).
// Pass 2: S again -> P=exp*inv -> lsP (bf16) -> PV MFMA + coalesced nt P-write.
__global__ __launch_bounds__(256)
void attn_fused(const ushort_t* __restrict__ qb, const ushort_t* __restrict__ kb,
                const ushort_t* __restrict__ vtb, float* __restrict__ attn,
                ushort_t* __restrict__ ao) {
  __shared__ __align__(16) char smem[34816 + 17408 + 512];
  ushort_t* lsK  = (ushort_t*)smem;                 // K staging (pass1/2)
  ushort_t* lsP  = (ushort_t*)smem;                 // P [128][136] (union w/ lsK)
  float*    lpart = (float*)smem;                   // [2][128] (pass1-end only)
  ushort_t* lsQV = (ushort_t*)(smem + 34816);       // Q staging, then V [64][136]
  float*    linvs = (float*)(smem + 34816 + 17408); // [128]

  const int bh = blockIdx.x;
  const int iT = 8 - blockIdx.y;          // heaviest tiles dispatch first
  const int tM = iT * 128;
  const int tid = threadIdx.x;
  const int wave = tid >> 6, lane = tid & 63;
  const int lr = lane & 15, quad = lane >> 4;
  const int waveM = (wave >> 1) * 64, waveN = (wave & 1) * 64;

  const ushort_t* Qg = qb + (size_t)bh * NPAD * DH;
  const ushort_t* Kg = kb + (size_t)bh * NPAD * DH;
  const ushort_t* Vg = vtb + (size_t)bh * DH * NPAD;
  float* attn_h = attn + (size_t)bh * ((size_t)SEQ_N * SEQ_N);

  // ---- stage Q once, keep as register fragments ----
#pragma unroll
  for (int p = 0; p < 4; ++p) {
    const int c = p * 256 + wave * 64 + lane;
    const int ks = c >> 9, n = (c >> 2) & 127, part = c & 3;
    gl_lds16(Qg + (size_t)(tM + n) * DH + ks * 32 + part * 8,
             lsQV + (size_t)(p * 256 + wave * 64) * 8);
  }
  __syncthreads();
  bf16x8 aq[4][2];
#pragma unroll
  for (int mi = 0; mi < 4; ++mi)
#pragma unroll
    for (int ks = 0; ks < 2; ++ks)
      aq[mi][ks] = *(const bf16x8*)(lsQV + ks * 4096 + (waveM + mi * 16 + lr) * 32 + quad * 8);
  __syncthreads();

  f32x4 acc[4][4];
  const f32x4 z4 = {0.f, 0.f, 0.f, 0.f};

  // ---- pass 1: row sums of exp ----
  float lsum[4][4];
#pragma unroll
  for (int mi = 0; mi < 4; ++mi)
#pragma unroll
    for (int r = 0; r < 4; ++r) lsum[mi][r] = 0.f;

  for (int j = 0; j <= iT; ++j) {
    __syncthreads();
#pragma unroll
    for (int p = 0; p < 4; ++p) {
      const int c = p * 256 + wave * 64 + lane;
      const int ks = c >> 9, n = (c >> 2) & 127, part = c & 3;
      gl_lds16(Kg + (size_t)(j * 128 + n) * DH + ks * 32 + part * 8,
               lsK + (size_t)(p * 256 + wave * 64) * 8);
    }
    __syncthreads();
#pragma unroll
    for (int mi = 0; mi < 4; ++mi)
#pragma unroll
      for (int ni = 0; ni < 4; ++ni) acc[mi][ni] = z4;
    __builtin_amdgcn_s_setprio(1);
#pragma unroll
    for (int ks = 0; ks < 2; ++ks) {
      bf16x8 bk[4];
#pragma unroll
      for (int ni = 0; ni < 4; ++ni)
        bk[ni] = *(const bf16x8*)(lsK + ks * 4096 + (waveN + ni * 16 + lr) * 32 + quad * 8);
#pragma unroll
      for (int mi = 0; mi < 4; ++mi)
#pragma unroll
        for (int ni = 0; ni < 4; ++ni)
          acc[mi][ni] = __builtin_amdgcn_mfma_f32_16x16x32_bf16(aq[mi][ks], bk[ni], acc[mi][ni], 0, 0, 0);
    }
    __builtin_amdgcn_s_setprio(0);
#pragma unroll
    for (int mi = 0; mi < 4; ++mi)
#pragma unroll
      for (int ni = 0; ni < 4; ++ni)
#pragma unroll
        for (int r = 0; r < 4; ++r) {
          const int row = tM + waveM + mi * 16 + quad * 4 + r;
          const int col = j * 128 + waveN + ni * 16 + lr;
          if (col <= row) lsum[mi][r] += __expf(acc[mi][ni][r] * 0.125f);
        }
  }
  // reduce across the 16 col-lanes, combine wave halves via LDS
#pragma unroll
  for (int mi = 0; mi < 4; ++mi)
#pragma unroll
    for (int r = 0; r < 4; ++r) {
      float s = lsum[mi][r];
      s += __shfl_xor(s, 1); s += __shfl_xor(s, 2);
      s += __shfl_xor(s, 4); s += __shfl_xor(s, 8);
      lsum[mi][r] = s;
    }
  __syncthreads();                // lsK reads done before lpart overwrites region0
  if (lr == 0) {
    const int wx = wave & 1;
#pragma unroll
    for (int mi = 0; mi < 4; ++mi)
#pragma unroll
      for (int r = 0; r < 4; ++r)
        lpart[wx * 128 + waveM + mi * 16 + quad * 4 + r] = lsum[mi][r];
  }
  __syncthreads();
  if (tid < 128) linvs[tid] = 1.0f / (lpart[tid] + lpart[128 + tid]);
  __syncthreads();
  float linv[4][4];
#pragma unroll
  for (int mi = 0; mi < 4; ++mi)
#pragma unroll
    for (int r = 0; r < 4; ++r)
      linv[mi][r] = linvs[waveM + mi * 16 + quad * 4 + r];

  // ---- pass 2: P write + PV ----
  f32x4 oacc[2][4];
#pragma unroll
  for (int i = 0; i < 2; ++i)
#pragma unroll
    for (int j = 0; j < 4; ++j) oacc[i][j] = z4;
  const int prow = wave * 32;             // O rows owned by this wave (PV A-op)
  const int wrow = wave * 32;             // rows this wave writes back to global
  const int lcol = lane;                  // 64 consecutive cols per store instr

  for (int j = 0; j <= iT; ++j) {
    __syncthreads();                      // prior iter's lsP/V reads complete
#pragma unroll
    for (int p = 0; p < 4; ++p) {
      const int c = p * 256 + wave * 64 + lane;
      const int ks = c >> 9, n = (c >> 2) & 127, part = c & 3;
      gl_lds16(Kg + (size_t)(j * 128 + n) * DH + ks * 32 + part * 8,
               lsK + (size_t)(p * 256 + wave * 64) * 8);
    }
    // V -> padded LDS [64][136]
#pragma unroll
    for (int p = 0; p < 4; ++p) {
      const int c = p * 256 + tid;
      const int n = c >> 4, klc = c & 15;
      const uint4 v = *(const uint4*)(Vg + (size_t)n * NPAD + j * 128 + klc * 8);
      *(uint4*)(lsQV + (size_t)n * 136 + klc * 8) = v;
    }
    __syncthreads();
#pragma unroll
    for (int mi = 0; mi < 4; ++mi)
#pragma unroll
      for (int ni = 0; ni < 4; ++ni) acc[mi][ni] = z4;
    __builtin_amdgcn_s_setprio(1);
#pragma unroll
    for (int ks = 0; ks < 2; ++ks) {
      bf16x8 bk[4];
#pragma unroll
      for (int ni = 0; ni < 4; ++ni)
        bk[ni] = *(const bf16x8*)(lsK + ks * 4096 + (waveN + ni * 16 + lr) * 32 + quad * 8);
#pragma unroll
      for (int mi = 0; mi < 4; ++mi)
#pragma unroll
        for (int ni = 0; ni < 4; ++ni)
          acc[mi][ni] = __builtin_amdgcn_mfma_f32_16x16x32_bf16(aq[mi][ks], bk[ni], acc[mi][ni], 0, 0, 0);
    }
    __builtin_amdgcn_s_setprio(0);
    __syncthreads();                      // all waves done reading lsK
#pragma unroll
    for (int mi = 0; mi < 4; ++mi)
#pragma unroll
      for (int ni = 0; ni < 4; ++ni)
#pragma unroll
        for (int r = 0; r < 4; ++r) {
          const int rowl = waveM + mi * 16 + quad * 4 + r;
          const int coll = waveN + ni * 16 + lr;
          const int row = tM + rowl;
          const int col = j * 128 + coll;
          const float pv = (col <= row) ? __expf(acc[mi][ni][r] * 0.125f) * linv[mi][r] : 0.f;
          lsP[(size_t)rowl * 136 + coll] = f2bf(pv);
        }
    __syncthreads();                      // lsP complete
    // PV MFMA
    __builtin_amdgcn_s_setprio(1);
#pragma unroll
    for (int ks = 0; ks < 4; ++ks) {
      bf16x8 ap[2], bv[4];
#pragma unroll
      for (int mi2 = 0; mi2 < 2; ++mi2)
        ap[mi2] = *(const bf16x8*)(lsP + (size_t)(prow + mi2 * 16 + lr) * 136 + ks * 32 + quad * 8);
#pragma unroll
      for (int ni = 0; ni < 4; ++ni)
        bv[ni] = *(const bf16x8*)(lsQV + (size_t)(ni * 16 + lr) * 136 + ks * 32 + quad * 8);
#pragma unroll
      for (int mi2 = 0; mi2 < 2; ++mi2)
#pragma unroll
        for (int ni = 0; ni < 4; ++ni)
          oacc[mi2][ni] = __builtin_amdgcn_mfma_f32_16x16x32_bf16(ap[mi2], bv[ni], oacc[mi2][ni], 0, 0, 0);
    }
    __builtin_amdgcn_s_setprio(0);
    // coalesced P write-back: per store instr, one row, 64 consecutive cols
#pragma unroll 8
    for (int rr = 0; rr < 32; ++rr) {
      const int grow = tM + wrow + rr;
      if (grow >= SEQ_N) break;           // wave-uniform
      const ushort_t* lrow = lsP + (size_t)(wrow + rr) * 136;
#pragma unroll
      for (int cb = 0; cb < 2; ++cb) {
        const int gcol = j * 128 + cb * 64 + lcol;
        union { unsigned u; float f; } cv;
        cv.u = ((unsigned)lrow[cb * 64 + lcol]) << 16;
        if (gcol < SEQ_N)
          __builtin_nontemporal_store(cv.f, attn_h + (size_t)grow * SEQ_N + gcol);
      }
    }
  }

  // ---- write O (bf16, token-major for proj GEMM) ----
  const int b_ = bh >> 4, h = bh & 15;
#pragma unroll
  for (int mi2 = 0; mi2 < 2; ++mi2)
#pragma unroll
    for (int ni = 0; ni < 4; ++ni)
#pragma unroll
      for (int r = 0; r < 4; ++r) {
        const int row = tM + prow + mi2 * 16 + quad * 4 + r;
        const int d = ni * 16 + lr;
        if (row < SEQ_N)
          ao[((size_t)row * 4 + b_) * CMODEL + h * DH + d] = f2bf(oacc[mi2][ni][r]);
      }

  // ---- zero strictly-upper attn region for these rows ----
  const int c0 = tM + 128;
  if (c0 <= 1024) {
    const int width = 1025 - c0;
    for (int r = wave; r < 128; r += 4) {
      float* rp = attn_h + (size_t)(tM + r) * SEQ_N + c0;
      int pre = ((16 - (int)(((uintptr_t)rp) & 15)) >> 2) & 3;
      if (pre > width) pre = width;
      for (int c = lane; c < pre; c += 64) rp[c] = 0.f;
      const int body = (width - pre) >> 2;
      f32x4* bp = (f32x4*)(rp + pre);
      const f32x4 zf4 = {0.f, 0.f, 0.f, 0.f};
      for (int c = lane; c < body; c += 64) __builtin_nontemporal_store(zf4, bp + c);
      for (int c = pre + body * 4 + lane; c < width; c += 64) rp[c] = 0.f;
    }
  }
}

// ---------------------------------------------------------------------------
extern "C" void kernel_launch(void* const* d_in, const int* in_sizes, int n_in,
                              void* d_out, int out_size, void* d_ws, size_t ws_size,
                              hipStream_t stream) {
  const float* x       = (const float*)d_in[0];
  const float* qkv_w   = (const float*)d_in[1];
  const float* proj_w  = (const float*)d_in[2];
  const float* proj_b  = (const float*)d_in[3];
  const float* ln1_g   = (const float*)d_in[4];
  const float* ln1_b   = (const float*)d_in[5];
  const float* ln2_g   = (const float*)d_in[6];
  const float* ln2_b   = (const float*)d_in[7];
  const float* fc_w    = (const float*)d_in[8];
  const float* fc_b    = (const float*)d_in[9];
  const float* cproj_w = (const float*)d_in[10];
  const float* cproj_b = (const float*)d_in[11];

  float* out_x = (float*)d_out;
  float* out_attn = out_x + (size_t)TTOK * CMODEL;

  char* p = (char*)d_ws;
  auto alloc = [&](size_t bytes) { char* r = p; p += (bytes + 255) & ~(size_t)255; return r; };
  ushort_t* ln1x  = (ushort_t*)alloc((size_t)MP * CMODEL * 2);
  ushort_t* wqkv  = (ushort_t*)alloc((size_t)3072 * 1024 * 2);
  ushort_t* wproj = (ushort_t*)alloc((size_t)1024 * 1024 * 2);
  ushort_t* wfc   = (ushort_t*)alloc((size_t)4096 * 1024 * 2);
  ushort_t* wcpr  = (ushort_t*)alloc((size_t)1024 * 4096 * 2);
  ushort_t* qb    = (ushort_t*)alloc((size_t)BH * NPAD * DH * 2);
  ushort_t* kb    = (ushort_t*)alloc((size_t)BH * NPAD * DH * 2);
  ushort_t* vtb   = (ushort_t*)alloc((size_t)BH * DH * NPAD * 2);
  ushort_t* aob   = (ushort_t*)alloc((size_t)MP * CMODEL * 2);
  float*    x1    = (float*)alloc((size_t)MP * CMODEL * 4);
  ushort_t* ln2x  = (ushort_t*)alloc((size_t)MP * CMODEL * 2);
  ushort_t* hb    = (ushort_t*)alloc((size_t)MP * 4096 * 2);
  (void)ws_size; (void)in_sizes; (void)n_in; (void)out_size;

  // all weights -> bf16, single launch
  cvt4<<<12288, 256, 0, stream>>>(qkv_w, wqkv, proj_w, wproj, fc_w, wfc, cproj_w, wcpr);

  // ln1; also initializes x1 = x + proj_b (split-K proj accumulates on top)
  ln_bf<<<TTOK, 256, 0, stream>>>(x, ln1_g, ln1_b, ln1x, proj_b, x1);

  // qkv = ln1x @ qkv_w.T  -> scatter q/k/v^T bf16
  gemm_bt<0><<<dim3(24, 33, 1), 256, 0, stream>>>(ln1x, 1024, wqkv, 1024, 1024,
      nullptr, nullptr, nullptr, nullptr, qb, kb, vtb);

  // fused attention: logits+softmax+attn-write+PV
  attn_fused<<<dim3(64, 9), 256, 0, stream>>>(qb, kb, vtb, out_attn, aob);

  // proj, split-K=2 (2x512): atomic accumulate into x1 (pre-init = x + proj_b)
  gemm_bt<5><<<dim3(8, 33, 2), 256, 0, stream>>>(aob, 1024, wproj, 1024, 512,
      nullptr, nullptr, x1, nullptr, nullptr, nullptr, nullptr);

  // ln2; also initializes out_x = x1 + cproj_b (split-K cproj accumulates on top)
  ln_bf<<<TTOK, 256, 0, stream>>>(x1, ln2_g, ln2_b, ln2x, cproj_b, out_x);

  // fc + bias + quickGELU -> bf16
  gemm_bt<4><<<dim3(32, 33, 1), 256, 0, stream>>>(ln2x, 1024, wfc, 1024, 1024,
      fc_b, nullptr, nullptr, hb, nullptr, nullptr, nullptr);

  // cproj, split-K=2 (2x2048): atomic accumulate into out_x (pre-init above)
  gemm_bt<5><<<dim3(8, 33, 2), 256, 0, stream>>>(hb, 4096, wcpr, 4096, 2048,
      nullptr, nullptr, out_x, nullptr, nullptr, nullptr, nullptr);
}

// Round 2
// 742.977 us; speedup vs baseline: 1.0398x; 1.0035x over previous
//
#include <hip/hip_runtime.h>

// ---------------------------------------------------------------------------
// ResidualAttentionBlock forward on MI355X (gfx950).
// Round 6: T1 XCD-bijective block swizzle (m204) on all GEMMs + attn
// (per-XCD L2 panel/head locality), ushort4 packed bf16 stores in cvt/ln.
// ---------------------------------------------------------------------------

typedef unsigned short ushort_t;
typedef __bf16 bf16x8 __attribute__((ext_vector_type(8)));
typedef float f32x4 __attribute__((ext_vector_type(4)));

#define SEQ_N   1025
#define CMODEL  1024
#define NHEAD   16
#define DH      64
#define TTOK    4100            // 1025*4 tokens
#define MP      4224            // tokens padded to 33*128
#define NPAD    1152            // seq padded to 9*128
#define BH      64              // 4*16 (batch*heads)

__device__ __forceinline__ ushort_t f2bf(float f) {
  union { float f; unsigned u; } v; v.f = f;
  unsigned r = v.u + 0x7fffu + ((v.u >> 16) & 1u);   // RNE
  return (ushort_t)(r >> 16);
}

__device__ __forceinline__ void gl_lds16(const void* g, void* s) {
  __builtin_amdgcn_global_load_lds(
      (const __attribute__((address_space(1))) unsigned int*)g,
      (__attribute__((address_space(3))) unsigned int*)s, 16, 0, 0);
}

// --------------------------- fp32 -> bf16 convert (all 4 weights) -----------
__global__ __launch_bounds__(256)
void cvt4(const float* __restrict__ s0, ushort_t* __restrict__ d0,
          const float* __restrict__ s1, ushort_t* __restrict__ d1,
          const float* __restrict__ s2, ushort_t* __restrict__ d2,
          const float* __restrict__ s3, ushort_t* __restrict__ d3) {
  const int b = blockIdx.x;
  const float* s; ushort_t* d; int off;
  if (b < 3072)      { s = s0; d = d0; off = b; }
  else if (b < 4096) { s = s1; d = d1; off = b - 3072; }
  else if (b < 8192) { s = s2; d = d2; off = b - 4096; }
  else               { s = s3; d = d3; off = b - 8192; }
  const int i = (off * 256 + threadIdx.x) * 4;
  const float4 f = *(const float4*)(s + i);
  ushort4 o;
  o.x = f2bf(f.x); o.y = f2bf(f.y); o.z = f2bf(f.z); o.w = f2bf(f.w);
  *(ushort4*)(d + i) = o;                          // one 8B store, coalesced
}

// --------------------------- LayerNorm (fp32 in, bf16 out) ------------------
// Optionally also writes resout[row] = row + rbias (residual+bias init for the
// following split-K GEMM's atomic accumulation).
__global__ __launch_bounds__(256)
void ln_bf(const float* __restrict__ xin, const float* __restrict__ g,
           const float* __restrict__ bb, ushort_t* __restrict__ out,
           const float* __restrict__ rbias, float* __restrict__ resout) {
  const int t = blockIdx.x;
  const float* row = xin + (size_t)t * CMODEL;
  const int base = threadIdx.x * 4;
  const float4 v = *(const float4*)(row + base);
  float s = v.x + v.y + v.z + v.w;
  float q = v.x * v.x + v.y * v.y + v.z * v.z + v.w * v.w;
#pragma unroll
  for (int off = 32; off > 0; off >>= 1) {
    s += __shfl_down(s, off);
    q += __shfl_down(q, off);
  }
  __shared__ float sh[8];
  const int wave = threadIdx.x >> 6, lane = threadIdx.x & 63;
  if (lane == 0) { sh[wave] = s; sh[4 + wave] = q; }
  __syncthreads();
  if (threadIdx.x == 0) {
    const float ts = sh[0] + sh[1] + sh[2] + sh[3];
    const float tq = sh[4] + sh[5] + sh[6] + sh[7];
    const float mean = ts * (1.f / CMODEL);
    const float var = tq * (1.f / CMODEL) - mean * mean;
    sh[0] = mean; sh[1] = rsqrtf(var + 1e-5f);
  }
  __syncthreads();
  const float mean = sh[0], rstd = sh[1];
  const float4 gg = *(const float4*)(g + base);
  const float4 bv = *(const float4*)(bb + base);
  ushort4 o;
  o.x = f2bf((v.x - mean) * rstd * gg.x + bv.x);
  o.y = f2bf((v.y - mean) * rstd * gg.y + bv.y);
  o.z = f2bf((v.z - mean) * rstd * gg.z + bv.z);
  o.w = f2bf((v.w - mean) * rstd * gg.w + bv.w);
  *(ushort4*)(out + (size_t)t * CMODEL + base) = o;  // one 8B store
  if (resout) {
    const float4 rb = *(const float4*)(rbias + base);
    float4 ro;
    ro.x = v.x + rb.x; ro.y = v.y + rb.y; ro.z = v.z + rb.z; ro.w = v.w + rb.w;
    *(float4*)(resout + (size_t)t * CMODEL + base) = ro;
  }
}

// --------------------------- bf16 MFMA GEMM (C = A * B^T) -------------------
// EPI: 0=qkv scatter  3=bias+residual->fp32  4=bias+quickgelu->bf16
//      5=split-K partial: atomicAdd into pre-initialized fp32 output.
// K is the per-chunk length; the swizzled z index selects the K-chunk.
// T1: bijective XCD swizzle (m204). All grids here are %8==0, so the simple
// form lin' = (lin&7)*(nwg/8) + lin>>3 is bijective. Consecutive lin' share
// the same A-row -> A-tiles stay hot in the XCD-private L2.
template <int EPI>
__global__ __launch_bounds__(256)
void gemm_bt(const ushort_t* __restrict__ A, int lda,
             const ushort_t* __restrict__ B, int ldb,
             int K,
             const float* __restrict__ bias, const float* __restrict__ res,
             float* __restrict__ outf, ushort_t* __restrict__ outb,
             ushort_t* __restrict__ oq, ushort_t* __restrict__ ok,
             ushort_t* __restrict__ ovt) {
  __shared__ __align__(16) ushort_t lsA[128 * 32];
  __shared__ __align__(16) ushort_t lsB[128 * 32];
  const int tid = threadIdx.x;
  const int wave = tid >> 6, lane = tid & 63;
  const int lr = lane & 15, quad = lane >> 4;

  // ---- XCD-bijective swizzle ----
  const int gx = gridDim.x, gy = gridDim.y;
  const int nwg = gx * gy * gridDim.z;
  int lin = blockIdx.x + gx * (blockIdx.y + gy * blockIdx.z);
  lin = (lin & 7) * (nwg >> 3) + (lin >> 3);
  const int bx = lin % gx;
  const int byz = lin / gx;
  const int by = byz % gy;
  const int bz = byz / gy;

  const int tM = by * 128, tN = bx * 128;
  const int kbase = bz * K;
  const int waveM = (wave >> 1) * 64, waveN = (wave & 1) * 64;

  f32x4 acc[4][4];
  const f32x4 z4 = {0.f, 0.f, 0.f, 0.f};
#pragma unroll
  for (int i = 0; i < 4; ++i)
#pragma unroll
    for (int j = 0; j < 4; ++j) acc[i][j] = z4;

  for (int k0 = 0; k0 < K; k0 += 32) {
    __syncthreads();
#pragma unroll
    for (int p = 0; p < 2; ++p) {
      const int idx = p * 256 + wave * 64 + lane;      // chunk 0..511 (16B each)
      const int row = idx >> 2, part = idx & 3;
      const int cb = (p * 256 + wave * 64) * 8;        // wave-uniform LDS base
      gl_lds16(A + (size_t)(tM + row) * lda + kbase + k0 + part * 8, lsA + cb);
      gl_lds16(B + (size_t)(tN + row) * ldb + kbase + k0 + part * 8, lsB + cb);
    }
    __syncthreads();
    bf16x8 af[4], bfr[4];
#pragma unroll
    for (int mi = 0; mi < 4; ++mi)
      af[mi] = *(const bf16x8*)(lsA + (waveM + mi * 16 + lr) * 32 + quad * 8);
#pragma unroll
    for (int ni = 0; ni < 4; ++ni)
      bfr[ni] = *(const bf16x8*)(lsB + (waveN + ni * 16 + lr) * 32 + quad * 8);
#pragma unroll
    for (int mi = 0; mi < 4; ++mi)
#pragma unroll
      for (int ni = 0; ni < 4; ++ni)
        acc[mi][ni] = __builtin_amdgcn_mfma_f32_16x16x32_bf16(af[mi], bfr[ni], acc[mi][ni], 0, 0, 0);
  }

#pragma unroll
  for (int mi = 0; mi < 4; ++mi) {
#pragma unroll
    for (int ni = 0; ni < 4; ++ni) {
#pragma unroll
      for (int r = 0; r < 4; ++r) {
        const int m = tM + waveM + mi * 16 + quad * 4 + r;
        const int n = tN + waveN + ni * 16 + lr;
        const float v = acc[mi][ni][r];
        if constexpr (EPI == 0) {                 // qkv: scatter to q/k/v^T (bf16)
          if (m < TTOK) {
            const int b_ = m & 3, ns = m >> 2;
            const int which = n >> 10, rem = n & 1023, h = rem >> 6, d = rem & 63;
            const int bh = b_ * NHEAD + h;
            const ushort_t bv = f2bf(v);
            if (which == 0)      oq[((size_t)bh * NPAD + ns) * DH + d] = bv;
            else if (which == 1) ok[((size_t)bh * NPAD + ns) * DH + d] = bv;
            else                 ovt[((size_t)bh * DH + d) * NPAD + ns] = bv;
          }
        } else if constexpr (EPI == 3) {          // + bias + residual -> fp32
          if (m < TTOK)
            outf[(size_t)m * CMODEL + n] = v + bias[n] + res[(size_t)m * CMODEL + n];
        } else if constexpr (EPI == 4) {          // + bias, quickGELU -> bf16
          if (m < TTOK) {
            const float zv = v + bias[n];
            outb[(size_t)m * 4096 + n] = f2bf(zv / (1.f + __expf(-1.702f * zv)));
          }
        } else if constexpr (EPI == 5) {          // split-K partial -> atomic
          if (m < TTOK)
            atomicAdd(outf + (size_t)m * CMODEL + n, v);
        }
      }
    }
  }
}

// --------------------------- fused causal attention -------------------------
// Grid (bh=64, it=9). Block = 256 thr. Per block: 128 Q rows of one head.
// T1 swizzle: logical (bh, iT) drawn y-major from the bijective remap so each
// XCD owns 8 complete heads -> that head's K/V/Q (~0.43 MB) stays L2-hot
// across its 9 blocks. Within a head, heaviest tiles still run first.
// LDS: region0 (34816B) = K staging UNION P tile UNION lpart;
//      region1 (17408B) = Q staging, then V [64][136]; region2 = linvs (512B).
// Pass 1: S=QK^T, accumulate row sums of exp(S*scale).
// Pass 2: S again -> P=exp*inv -> lsP (bf16) -> PV MFMA + coalesced nt P-write.
__global__ __launch_bounds__(256)
void attn_fused(const ushort_t* __restrict__ qb, const ushort_t* __restrict__ kb,
                const ushort_t* __restrict__ vtb, float* __restrict__ attn,
                ushort_t* __restrict__ ao) {
  __shared__ __align__(16) char smem[34816 + 17408 + 512];
  ushort_t* lsK  = (ushort_t*)smem;                 // K staging (pass1/2)
  ushort_t* lsP  = (ushort_t*)smem;                 // P [128][136] (union w/ lsK)
  float*    lpart = (float*)smem;                   // [2][128] (pass1-end only)
  ushort_t* lsQV = (ushort_t*)(smem + 34816);       // Q staging, then V [64][136]
  float*    linvs = (float*)(smem + 34816 + 17408); // [128]

  // ---- XCD-bijective swizzle: 576 blocks = 8 XCDs x 72 (8 heads x 9 tiles) --
  int lin = blockIdx.x + 64 * blockIdx.y;
  lin = (lin & 7) * 72 + (lin >> 3);
  const int bh = lin / 9;
  const int iT = 8 - (lin % 9);           // heaviest tile of each head first
  const int tM = iT * 128;
  const int tid = threadIdx.x;
  const int wave = tid >> 6, lane = tid & 63;
  const int lr = lane & 15, quad = lane >> 4;
  const int waveM = (wave >> 1) * 64, waveN = (wave & 1) * 64;

  const ushort_t* Qg = qb + (size_t)bh * NPAD * DH;
  const ushort_t* Kg = kb + (size_t)bh * NPAD * DH;
  const ushort_t* Vg = vtb + (size_t)bh * DH * NPAD;
  float* attn_h = attn + (size_t)bh * ((size_t)SEQ_N * SEQ_N);

  // ---- stage Q once, keep as register fragments ----
#pragma unroll
  for (int p = 0; p < 4; ++p) {
    const int c = p * 256 + wave * 64 + lane;
    const int ks = c >> 9, n = (c >> 2) & 127, part = c & 3;
    gl_lds16(Qg + (size_t)(tM + n) * DH + ks * 32 + part * 8,
             lsQV + (size_t)(p * 256 + wave * 64) * 8);
  }
  __syncthreads();
  bf16x8 aq[4][2];
#pragma unroll
  for (int mi = 0; mi < 4; ++mi)
#pragma unroll
    for (int ks = 0; ks < 2; ++ks)
      aq[mi][ks] = *(const bf16x8*)(lsQV + ks * 4096 + (waveM + mi * 16 + lr) * 32 + quad * 8);
  __syncthreads();

  f32x4 acc[4][4];
  const f32x4 z4 = {0.f, 0.f, 0.f, 0.f};

  // ---- pass 1: row sums of exp ----
  float lsum[4][4];
#pragma unroll
  for (int mi = 0; mi < 4; ++mi)
#pragma unroll
    for (int r = 0; r < 4; ++r) lsum[mi][r] = 0.f;

  for (int j = 0; j <= iT; ++j) {
    __syncthreads();
#pragma unroll
    for (int p = 0; p < 4; ++p) {
      const int c = p * 256 + wave * 64 + lane;
      const int ks = c >> 9, n = (c >> 2) & 127, part = c & 3;
      gl_lds16(Kg + (size_t)(j * 128 + n) * DH + ks * 32 + part * 8,
               lsK + (size_t)(p * 256 + wave * 64) * 8);
    }
    __syncthreads();
#pragma unroll
    for (int mi = 0; mi < 4; ++mi)
#pragma unroll
      for (int ni = 0; ni < 4; ++ni) acc[mi][ni] = z4;
    __builtin_amdgcn_s_setprio(1);
#pragma unroll
    for (int ks = 0; ks < 2; ++ks) {
      bf16x8 bk[4];
#pragma unroll
      for (int ni = 0; ni < 4; ++ni)
        bk[ni] = *(const bf16x8*)(lsK + ks * 4096 + (waveN + ni * 16 + lr) * 32 + quad * 8);
#pragma unroll
      for (int mi = 0; mi < 4; ++mi)
#pragma unroll
        for (int ni = 0; ni < 4; ++ni)
          acc[mi][ni] = __builtin_amdgcn_mfma_f32_16x16x32_bf16(aq[mi][ks], bk[ni], acc[mi][ni], 0, 0, 0);
    }
    __builtin_amdgcn_s_setprio(0);
#pragma unroll
    for (int mi = 0; mi < 4; ++mi)
#pragma unroll
      for (int ni = 0; ni < 4; ++ni)
#pragma unroll
        for (int r = 0; r < 4; ++r) {
          const int row = tM + waveM + mi * 16 + quad * 4 + r;
          const int col = j * 128 + waveN + ni * 16 + lr;
          if (col <= row) lsum[mi][r] += __expf(acc[mi][ni][r] * 0.125f);
        }
  }
  // reduce across the 16 col-lanes, combine wave halves via LDS
#pragma unroll
  for (int mi = 0; mi < 4; ++mi)
#pragma unroll
    for (int r = 0; r < 4; ++r) {
      float s = lsum[mi][r];
      s += __shfl_xor(s, 1); s += __shfl_xor(s, 2);
      s += __shfl_xor(s, 4); s += __shfl_xor(s, 8);
      lsum[mi][r] = s;
    }
  __syncthreads();                // lsK reads done before lpart overwrites region0
  if (lr == 0) {
    const int wx = wave & 1;
#pragma unroll
    for (int mi = 0; mi < 4; ++mi)
#pragma unroll
      for (int r = 0; r < 4; ++r)
        lpart[wx * 128 + waveM + mi * 16 + quad * 4 + r] = lsum[mi][r];
  }
  __syncthreads();
  if (tid < 128) linvs[tid] = 1.0f / (lpart[tid] + lpart[128 + tid]);
  __syncthreads();
  float linv[4][4];
#pragma unroll
  for (int mi = 0; mi < 4; ++mi)
#pragma unroll
    for (int r = 0; r < 4; ++r)
      linv[mi][r] = linvs[waveM + mi * 16 + quad * 4 + r];

  // ---- pass 2: P write + PV ----
  f32x4 oacc[2][4];
#pragma unroll
  for (int i = 0; i < 2; ++i)
#pragma unroll
    for (int j = 0; j < 4; ++j) oacc[i][j] = z4;
  const int prow = wave * 32;             // O rows owned by this wave (PV A-op)
  const int wrow = wave * 32;             // rows this wave writes back to global
  const int lcol = lane;                  // 64 consecutive cols per store instr

  for (int j = 0; j <= iT; ++j) {
    __syncthreads();                      // prior iter's lsP/V reads complete
#pragma unroll
    for (int p = 0; p < 4; ++p) {
      const int c = p * 256 + wave * 64 + lane;
      const int ks = c >> 9, n = (c >> 2) & 127, part = c & 3;
      gl_lds16(Kg + (size_t)(j * 128 + n) * DH + ks * 32 + part * 8,
               lsK + (size_t)(p * 256 + wave * 64) * 8);
    }
    // V -> padded LDS [64][136]
#pragma unroll
    for (int p = 0; p < 4; ++p) {
      const int c = p * 256 + tid;
      const int n = c >> 4, klc = c & 15;
      const uint4 v = *(const uint4*)(Vg + (size_t)n * NPAD + j * 128 + klc * 8);
      *(uint4*)(lsQV + (size_t)n * 136 + klc * 8) = v;
    }
    __syncthreads();
#pragma unroll
    for (int mi = 0; mi < 4; ++mi)
#pragma unroll
      for (int ni = 0; ni < 4; ++ni) acc[mi][ni] = z4;
    __builtin_amdgcn_s_setprio(1);
#pragma unroll
    for (int ks = 0; ks < 2; ++ks) {
      bf16x8 bk[4];
#pragma unroll
      for (int ni = 0; ni < 4; ++ni)
        bk[ni] = *(const bf16x8*)(lsK + ks * 4096 + (waveN + ni * 16 + lr) * 32 + quad * 8);
#pragma unroll
      for (int mi = 0; mi < 4; ++mi)
#pragma unroll
        for (int ni = 0; ni < 4; ++ni)
          acc[mi][ni] = __builtin_amdgcn_mfma_f32_16x16x32_bf16(aq[mi][ks], bk[ni], acc[mi][ni], 0, 0, 0);
    }
    __builtin_amdgcn_s_setprio(0);
    __syncthreads();                      // all waves done reading lsK
#pragma unroll
    for (int mi = 0; mi < 4; ++mi)
#pragma unroll
      for (int ni = 0; ni < 4; ++ni)
#pragma unroll
        for (int r = 0; r < 4; ++r) {
          const int rowl = waveM + mi * 16 + quad * 4 + r;
          const int coll = waveN + ni * 16 + lr;
          const int row = tM + rowl;
          const int col = j * 128 + coll;
          const float pv = (col <= row) ? __expf(acc[mi][ni][r] * 0.125f) * linv[mi][r] : 0.f;
          lsP[(size_t)rowl * 136 + coll] = f2bf(pv);
        }
    __syncthreads();                      // lsP complete
    // PV MFMA
    __builtin_amdgcn_s_setprio(1);
#pragma unroll
    for (int ks = 0; ks < 4; ++ks) {
      bf16x8 ap[2], bv[4];
#pragma unroll
      for (int mi2 = 0; mi2 < 2; ++mi2)
        ap[mi2] = *(const bf16x8*)(lsP + (size_t)(prow + mi2 * 16 + lr) * 136 + ks * 32 + quad * 8);
#pragma unroll
      for (int ni = 0; ni < 4; ++ni)
        bv[ni] = *(const bf16x8*)(lsQV + (size_t)(ni * 16 + lr) * 136 + ks * 32 + quad * 8);
#pragma unroll
      for (int mi2 = 0; mi2 < 2; ++mi2)
#pragma unroll
        for (int ni = 0; ni < 4; ++ni)
          oacc[mi2][ni] = __builtin_amdgcn_mfma_f32_16x16x32_bf16(ap[mi2], bv[ni], oacc[mi2][ni], 0, 0, 0);
    }
    __builtin_amdgcn_s_setprio(0);
    // coalesced P write-back: per store instr, one row, 64 consecutive cols
#pragma unroll 8
    for (int rr = 0; rr < 32; ++rr) {
      const int grow = tM + wrow + rr;
      if (grow >= SEQ_N) break;           // wave-uniform
      const ushort_t* lrow = lsP + (size_t)(wrow + rr) * 136;
#pragma unroll
      for (int cb = 0; cb < 2; ++cb) {
        const int gcol = j * 128 + cb * 64 + lcol;
        union { unsigned u; float f; } cv;
        cv.u = ((unsigned)lrow[cb * 64 + lcol]) << 16;
        if (gcol < SEQ_N)
          __builtin_nontemporal_store(cv.f, attn_h + (size_t)grow * SEQ_N + gcol);
      }
    }
  }

  // ---- write O (bf16, token-major for proj GEMM) ----
  const int b_ = bh >> 4, h = bh & 15;
#pragma unroll
  for (int mi2 = 0; mi2 < 2; ++mi2)
#pragma unroll
    for (int ni = 0; ni < 4; ++ni)
#pragma unroll
      for (int r = 0; r < 4; ++r) {
        const int row = tM + prow + mi2 * 16 + quad * 4 + r;
        const int d = ni * 16 + lr;
        if (row < SEQ_N)
          ao[((size_t)row * 4 + b_) * CMODEL + h * DH + d] = f2bf(oacc[mi2][ni][r]);
      }

  // ---- zero strictly-upper attn region for these rows ----
  const int c0 = tM + 128;
  if (c0 <= 1024) {
    const int width = 1025 - c0;
    for (int r = wave; r < 128; r += 4) {
      float* rp = attn_h + (size_t)(tM + r) * SEQ_N + c0;
      int pre = ((16 - (int)(((uintptr_t)rp) & 15)) >> 2) & 3;
      if (pre > width) pre = width;
      for (int c = lane; c < pre; c += 64) rp[c] = 0.f;
      const int body = (width - pre) >> 2;
      f32x4* bp = (f32x4*)(rp + pre);
      const f32x4 zf4 = {0.f, 0.f, 0.f, 0.f};
      for (int c = lane; c < body; c += 64) __builtin_nontemporal_store(zf4, bp + c);
      for (int c = pre + body * 4 + lane; c < width; c += 64) rp[c] = 0.f;
    }
  }
}

// ---------------------------------------------------------------------------
extern "C" void kernel_launch(void* const* d_in, const int* in_sizes, int n_in,
                              void* d_out, int out_size, void* d_ws, size_t ws_size,
                              hipStream_t stream) {
  const float* x       = (const float*)d_in[0];
  const float* qkv_w   = (const float*)d_in[1];
  const float* proj_w  = (const float*)d_in[2];
  const float* proj_b  = (const float*)d_in[3];
  const float* ln1_g   = (const float*)d_in[4];
  const float* ln1_b   = (const float*)d_in[5];
  const float* ln2_g   = (const float*)d_in[6];
  const float* ln2_b   = (const float*)d_in[7];
  const float* fc_w    = (const float*)d_in[8];
  const float* fc_b    = (const float*)d_in[9];
  const float* cproj_w = (const float*)d_in[10];
  const float* cproj_b = (const float*)d_in[11];

  float* out_x = (float*)d_out;
  float* out_attn = out_x + (size_t)TTOK * CMODEL;

  char* p = (char*)d_ws;
  auto alloc = [&](size_t bytes) { char* r = p; p += (bytes + 255) & ~(size_t)255; return r; };
  ushort_t* ln1x  = (ushort_t*)alloc((size_t)MP * CMODEL * 2);
  ushort_t* wqkv  = (ushort_t*)alloc((size_t)3072 * 1024 * 2);
  ushort_t* wproj = (ushort_t*)alloc((size_t)1024 * 1024 * 2);
  ushort_t* wfc   = (ushort_t*)alloc((size_t)4096 * 1024 * 2);
  ushort_t* wcpr  = (ushort_t*)alloc((size_t)1024 * 4096 * 2);
  ushort_t* qb    = (ushort_t*)alloc((size_t)BH * NPAD * DH * 2);
  ushort_t* kb    = (ushort_t*)alloc((size_t)BH * NPAD * DH * 2);
  ushort_t* vtb   = (ushort_t*)alloc((size_t)BH * DH * NPAD * 2);
  ushort_t* aob   = (ushort_t*)alloc((size_t)MP * CMODEL * 2);
  float*    x1    = (float*)alloc((size_t)MP * CMODEL * 4);
  ushort_t* ln2x  = (ushort_t*)alloc((size_t)MP * CMODEL * 2);
  ushort_t* hb    = (ushort_t*)alloc((size_t)MP * 4096 * 2);
  (void)ws_size; (void)in_sizes; (void)n_in; (void)out_size;

  // all weights -> bf16, single launch
  cvt4<<<12288, 256, 0, stream>>>(qkv_w, wqkv, proj_w, wproj, fc_w, wfc, cproj_w, wcpr);

  // ln1; also initializes x1 = x + proj_b (split-K proj accumulates on top)
  ln_bf<<<TTOK, 256, 0, stream>>>(x, ln1_g, ln1_b, ln1x, proj_b, x1);

  // qkv = ln1x @ qkv_w.T  -> scatter q/k/v^T bf16   (792 blocks, %8==0)
  gemm_bt<0><<<dim3(24, 33, 1), 256, 0, stream>>>(ln1x, 1024, wqkv, 1024, 1024,
      nullptr, nullptr, nullptr, nullptr, qb, kb, vtb);

  // fused attention: logits+softmax+attn-write+PV  (576 blocks, %8==0)
  attn_fused<<<dim3(64, 9), 256, 0, stream>>>(qb, kb, vtb, out_attn, aob);

  // proj, split-K=2 (2x512): atomic accumulate into x1 (pre-init = x + proj_b)
  gemm_bt<5><<<dim3(8, 33, 2), 256, 0, stream>>>(aob, 1024, wproj, 1024, 512,
      nullptr, nullptr, x1, nullptr, nullptr, nullptr, nullptr);

  // ln2; also initializes out_x = x1 + cproj_b (split-K cproj accumulates on top)
  ln_bf<<<TTOK, 256, 0, stream>>>(x1, ln2_g, ln2_b, ln2x, cproj_b, out_x);

  // fc + bias + quickGELU -> bf16   (1056 blocks, %8==0)
  gemm_bt<4><<<dim3(32, 33, 1), 256, 0, stream>>>(ln2x, 1024, wfc, 1024, 1024,
      fc_b, nullptr, nullptr, hb, nullptr, nullptr, nullptr);

  // cproj, split-K=2 (2x2048): atomic accumulate into out_x (pre-init above)
  gemm_bt<5><<<dim3(8, 33, 2), 256, 0, stream>>>(hb, 4096, wcpr, 4096, 2048,
      nullptr, nullptr, out_x, nullptr, nullptr, nullptr, nullptr);
}